// Round 1
// baseline (19.966 us; speedup 1.0000x reference)
//
#include <hip/hip_runtime.h>

// Kernel 1: per-row inclusive cumsum of (token == sep && s < len).
// One block (1024 threads) per batch row; 4 elements per thread per chunk,
// Hillis-Steele scan in LDS, carry across chunks.
__global__ void seg_scan_kernel(const int* __restrict__ tokens,
                                const int* __restrict__ lengths,
                                const int* __restrict__ sep_p,
                                int* __restrict__ seg,
                                int S) {
    const int b = blockIdx.x;
    const int tid = threadIdx.x;           // 0..1023
    const int sep = sep_p[0];
    const int len = lengths[b];
    const int* trow = tokens + (size_t)b * S;
    int* srow = seg + (size_t)b * S;

    __shared__ int lds[1024];
    __shared__ int carry_s;
    if (tid == 0) carry_s = 0;
    __syncthreads();

    const int CHUNK = 4096; // 1024 threads * 4 elems
    for (int base = 0; base < S; base += CHUNK) {
        const int s0 = base + tid * 4;
        int v[4];
        int cnt = 0;
#pragma unroll
        for (int k = 0; k < 4; ++k) {
            int s = s0 + k;
            int ind = 0;
            if (s < S) {
                int t = trow[s];
                ind = (t == sep && s < len) ? 1 : 0;
            }
            cnt += ind;
            v[k] = cnt;   // local inclusive prefix within this thread's 4
        }
        // Block-wide inclusive scan of cnt over 1024 threads (Hillis-Steele).
        lds[tid] = cnt;
        __syncthreads();
        int sum = cnt;
        for (int off = 1; off < 1024; off <<= 1) {
            int add = (tid >= off) ? lds[tid - off] : 0;
            __syncthreads();          // all reads done before writes
            sum += add;
            lds[tid] = sum;
            __syncthreads();
        }
        const int excl = sum - cnt;   // exclusive prefix for this thread
        const int carry = carry_s;
#pragma unroll
        for (int k = 0; k < 4; ++k) {
            int s = s0 + k;
            if (s < S) srow[s] = carry + excl + v[k];
        }
        __syncthreads();
        if (tid == 1023) carry_s = carry + sum;   // total of this chunk
        __syncthreads();
    }
}

// Kernel 2: out[pos, lane4] = tok_emb[token] + seg_emb[seg], zeroed when padded.
// Flat grid over B*S*(D/4) float4 elements; coalesced float4 read/write.
__global__ void gather_add_kernel(const float4* __restrict__ tok_emb,
                                  const float4* __restrict__ seg_emb,
                                  const int* __restrict__ tokens,
                                  const int* __restrict__ lengths,
                                  const int* __restrict__ seg,
                                  float4* __restrict__ out,
                                  int S, int D4, int nseg, int V, long long total) {
    long long tid = (long long)blockIdx.x * blockDim.x + threadIdx.x;
    if (tid >= total) return;
    const int lane = (int)(tid % D4);
    const int pos  = (int)(tid / D4);
    const int b = pos / S;
    const int s = pos % S;

    float4 r = make_float4(0.f, 0.f, 0.f, 0.f);
    if (s < lengths[b]) {
        int t = tokens[pos];
        if (t < 0) t = 0;
        if (t >= V) t = V - 1;          // JAX clamp-gather semantics
        int sg = seg[pos];
        if (sg < 0) sg = 0;
        if (sg >= nseg) sg = nseg - 1;  // clamp (cumsum could exceed NSEG)
        const float4 a = tok_emb[(size_t)t * D4 + lane];
        const float4 e = seg_emb[(size_t)sg * D4 + lane];
        r = make_float4(a.x + e.x, a.y + e.y, a.z + e.z, a.w + e.w);
    }
    out[(size_t)pos * D4 + lane] = r;
}

extern "C" void kernel_launch(void* const* d_in, const int* in_sizes, int n_in,
                              void* d_out, int out_size, void* d_ws, size_t ws_size,
                              hipStream_t stream) {
    const float* tok_emb = (const float*)d_in[0];   // [V, D]
    const float* seg_emb = (const float*)d_in[1];   // [NSEG, D]
    const int*   tokens  = (const int*)d_in[2];     // [B, S]
    const int*   lengths = (const int*)d_in[3];     // [B]
    const int*   sep_p   = (const int*)d_in[4];     // scalar

    const int B  = in_sizes[3];
    const int BS = in_sizes[2];
    const int S  = BS / B;
    const int D  = out_size / BS;
    const int nseg = in_sizes[1] / D;
    const int V    = in_sizes[0] / D;
    const int D4   = D / 4;

    int* seg_ws = (int*)d_ws;                       // B*S ints

    seg_scan_kernel<<<B, 1024, 0, stream>>>(tokens, lengths, sep_p, seg_ws, S);

    const long long total = (long long)BS * D4;     // float4 elements of output
    const int block = 256;
    const int grid  = (int)((total + block - 1) / block);
    gather_add_kernel<<<grid, block, 0, stream>>>(
        (const float4*)tok_emb, (const float4*)seg_emb,
        tokens, lengths, seg_ws, (float4*)d_out,
        S, D4, nseg, V, total);
}

// Round 3
// 17.346 us; speedup vs baseline: 1.1510x; 1.1510x over previous
//
#include <hip/hip_runtime.h>

typedef float f32x4 __attribute__((ext_vector_type(4)));
typedef int   i32x4 __attribute__((ext_vector_type(4)));

// ---------------------------------------------------------------------------
// Kernel 1: per-row inclusive cumsum of (token == sep && s < len).
// One 1024-thread block per batch row. 4 tokens/thread, wave64 shuffle scan
// (6 steps), 16 wave totals combined via LDS. 2 barriers per chunk.
// Writes seg id, or -1 sentinel for padded positions (s >= len).
// ---------------------------------------------------------------------------
__global__ __launch_bounds__(1024) void seg_scan_kernel(
        const int* __restrict__ tokens,
        const int* __restrict__ lengths,
        const int* __restrict__ sep_p,
        int* __restrict__ seg,
        int S) {
    const int b    = blockIdx.x;
    const int tid  = threadIdx.x;          // 0..1023
    const int lane = tid & 63;
    const int wave = tid >> 6;             // 0..15
    const int sep  = sep_p[0];
    const int len  = lengths[b];
    const int* trow = tokens + (size_t)b * S;
    int* srow       = seg    + (size_t)b * S;

    __shared__ int wsum[16];
    __shared__ int carry_s;
    if (tid == 0) carry_s = 0;

    const int CHUNK = 4096;                // 1024 threads * 4
    for (int base = 0; base < S; base += CHUNK) {
        const int s0 = base + tid * 4;
        int t0 = 0, t1 = 0, t2 = 0, t3 = 0;
        if (s0 + 3 < S) {
            const i32x4 t4 = *reinterpret_cast<const i32x4*>(trow + s0);
            t0 = t4.x; t1 = t4.y; t2 = t4.z; t3 = t4.w;
        } else {
            if (s0 + 0 < S) t0 = trow[s0 + 0];
            if (s0 + 1 < S) t1 = trow[s0 + 1];
            if (s0 + 2 < S) t2 = trow[s0 + 2];
            if (s0 + 3 < S) t3 = trow[s0 + 3];
        }
        // local inclusive prefix over the 4 (mask: only valid positions count)
        int v0 = ((t0 == sep) && (s0 + 0 < len)) ? 1 : 0;
        int v1 = v0 + (((t1 == sep) && (s0 + 1 < len)) ? 1 : 0);
        int v2 = v1 + (((t2 == sep) && (s0 + 2 < len)) ? 1 : 0);
        int v3 = v2 + (((t3 == sep) && (s0 + 3 < len)) ? 1 : 0);
        const int cnt = v3;

        // wave64 inclusive scan of cnt
        int ws = cnt;
        #pragma unroll
        for (int off = 1; off < 64; off <<= 1) {
            int up = __shfl_up(ws, off);
            if (lane >= off) ws += up;
        }
        if (lane == 63) wsum[wave] = ws;
        __syncthreads();                    // B1: wave totals visible

        int wave_excl = 0, total = 0;
        #pragma unroll
        for (int w = 0; w < 16; ++w) {
            int t = wsum[w];
            if (w < wave) wave_excl += t;
            total += t;
        }
        const int carry = carry_s;          // safe: prev iter's update barriered
        const int excl  = carry + wave_excl + (ws - cnt);

        if (s0 + 3 < S && s0 + 4 <= len) {
            // fast path: all 4 valid
            i32x4 o; o.x = excl + v0; o.y = excl + v1; o.z = excl + v2; o.w = excl + v3;
            *reinterpret_cast<i32x4*>(srow + s0) = o;
        } else {
            if (s0 + 0 < S) srow[s0 + 0] = (s0 + 0 < len) ? excl + v0 : -1;
            if (s0 + 1 < S) srow[s0 + 1] = (s0 + 1 < len) ? excl + v1 : -1;
            if (s0 + 2 < S) srow[s0 + 2] = (s0 + 2 < len) ? excl + v2 : -1;
            if (s0 + 3 < S) srow[s0 + 3] = (s0 + 3 < len) ? excl + v3 : -1;
        }
        __syncthreads();                    // B2: all carry reads done
        if (tid == 0) carry_s = carry + total;
    }
}

// ---------------------------------------------------------------------------
// Kernel 2 (pow2 fast path): out[pos,lane] = tok_emb[token] + seg_emb[seg],
// zero when seg sentinel < 0. Shift/mask indexing, nontemporal f32x4 stores.
// ---------------------------------------------------------------------------
__global__ __launch_bounds__(256) void gather_add_pow2_kernel(
        const f32x4* __restrict__ tok_emb,
        const f32x4* __restrict__ seg_emb,
        const int* __restrict__ tokens,
        const int* __restrict__ seg,
        f32x4* __restrict__ out,
        int d4_shift, int nseg, int V, long long total) {
    const long long tid = (long long)blockIdx.x * blockDim.x + threadIdx.x;
    if (tid >= total) return;
    const int  lane = (int)(tid & ((1 << d4_shift) - 1));
    const long long pos = tid >> d4_shift;      // wave-uniform when d4 >= 64

    const int sg_raw = seg[pos];
    f32x4 r = (f32x4)0.f;
    if (sg_raw >= 0) {
        int t = tokens[pos];
        t = (t < 0) ? 0 : ((t >= V) ? V - 1 : t);        // JAX clamp-gather
        int sg = (sg_raw >= nseg) ? nseg - 1 : sg_raw;
        const f32x4 a = tok_emb[((size_t)t  << d4_shift) + lane];
        const f32x4 e = seg_emb[((size_t)sg << d4_shift) + lane];
        r = a + e;
    }
    __builtin_nontemporal_store(r, &out[(pos << d4_shift) + lane]);
}

// Generic fallback (non-pow2 D4): div/mod version.
__global__ __launch_bounds__(256) void gather_add_div_kernel(
        const f32x4* __restrict__ tok_emb,
        const f32x4* __restrict__ seg_emb,
        const int* __restrict__ tokens,
        const int* __restrict__ seg,
        f32x4* __restrict__ out,
        int D4, int nseg, int V, long long total) {
    const long long tid = (long long)blockIdx.x * blockDim.x + threadIdx.x;
    if (tid >= total) return;
    const int lane = (int)(tid % D4);
    const long long pos = tid / D4;

    const int sg_raw = seg[pos];
    f32x4 r = (f32x4)0.f;
    if (sg_raw >= 0) {
        int t = tokens[pos];
        t = (t < 0) ? 0 : ((t >= V) ? V - 1 : t);
        int sg = (sg_raw >= nseg) ? nseg - 1 : sg_raw;
        const f32x4 a = tok_emb[(size_t)t * D4 + lane];
        const f32x4 e = seg_emb[(size_t)sg * D4 + lane];
        r = a + e;
    }
    __builtin_nontemporal_store(r, &out[(size_t)pos * D4 + lane]);
}

extern "C" void kernel_launch(void* const* d_in, const int* in_sizes, int n_in,
                              void* d_out, int out_size, void* d_ws, size_t ws_size,
                              hipStream_t stream) {
    const float* tok_emb = (const float*)d_in[0];   // [V, D]
    const float* seg_emb = (const float*)d_in[1];   // [NSEG, D]
    const int*   tokens  = (const int*)d_in[2];     // [B, S]
    const int*   lengths = (const int*)d_in[3];     // [B]
    const int*   sep_p   = (const int*)d_in[4];     // scalar

    const int B    = in_sizes[3];
    const int BS   = in_sizes[2];
    const int S    = BS / B;
    const int D    = out_size / BS;
    const int nseg = in_sizes[1] / D;
    const int V    = in_sizes[0] / D;
    const int D4   = D / 4;

    int* seg_ws = (int*)d_ws;                       // B*S ints

    seg_scan_kernel<<<B, 1024, 0, stream>>>(tokens, lengths, sep_p, seg_ws, S);

    const long long total = (long long)BS * D4;     // f32x4 elements
    const int block = 256;
    const int grid  = (int)((total + block - 1) / block);

    if ((D4 & (D4 - 1)) == 0) {
        int sh = 0;
        while ((1 << sh) < D4) ++sh;
        gather_add_pow2_kernel<<<grid, block, 0, stream>>>(
            (const f32x4*)tok_emb, (const f32x4*)seg_emb,
            tokens, seg_ws, (f32x4*)d_out, sh, nseg, V, total);
    } else {
        gather_add_div_kernel<<<grid, block, 0, stream>>>(
            (const f32x4*)tok_emb, (const f32x4*)seg_emb,
            tokens, seg_ws, (f32x4*)d_out, D4, nseg, V, total);
    }
}

// Round 4
// 13.004 us; speedup vs baseline: 1.5353x; 1.3339x over previous
//
#include <hip/hip_runtime.h>

typedef float f32x4 __attribute__((ext_vector_type(4)));
typedef int   i32x4 __attribute__((ext_vector_type(4)));

// ---------------------------------------------------------------------------
// Fused kernel (fast path: D == 256 i.e. D4 == 64, S % TP == 0, block = 256).
// Each block: TP consecutive positions of one batch row.
//   Phase 1: all 256 threads count sep-hits in row prefix [0, p0) (int4 loads)
//   Phase 2: wave 0 does TP-wide inclusive scan -> seg ids (+ -1 sentinel)
//   Phase 3: each wave gathers+adds+stores one position per iteration
// ---------------------------------------------------------------------------
template <int TP>
__global__ __launch_bounds__(256) void fused_embed_kernel(
        const f32x4* __restrict__ tok_emb,
        const f32x4* __restrict__ seg_emb,
        const int* __restrict__ tokens,
        const int* __restrict__ lengths,
        const int* __restrict__ sep_p,
        f32x4* __restrict__ out,
        int S, int nseg, int V) {
    const int tid  = threadIdx.x;
    const int lane = tid & 63;
    const int wave = tid >> 6;               // 0..3
    const int tiles_per_row = S / TP;
    const int b    = blockIdx.x / tiles_per_row;
    const int p0   = (blockIdx.x % tiles_per_row) * TP;
    const int sep  = sep_p[0];
    const int len  = lengths[b];
    const int* trow = tokens + (size_t)b * S;

    __shared__ int wsum[4];
    __shared__ int seg_lds[TP];
    __shared__ int tok_lds[TP];

    // Phase 1: count sep occurrences in [0, p0) intersect [0, len).
    int cnt = 0;
    for (int i = tid * 4; i < p0; i += 1024) {       // p0 % 4 == 0 (TP mult of 4)
        const i32x4 t4 = *reinterpret_cast<const i32x4*>(trow + i);
        cnt += (t4.x == sep && i + 0 < len) ? 1 : 0;
        cnt += (t4.y == sep && i + 1 < len) ? 1 : 0;
        cnt += (t4.z == sep && i + 2 < len) ? 1 : 0;
        cnt += (t4.w == sep && i + 3 < len) ? 1 : 0;
    }
    #pragma unroll
    for (int off = 32; off; off >>= 1) cnt += __shfl_xor(cnt, off);
    if (lane == 0) wsum[wave] = cnt;
    __syncthreads();                                  // B1
    const int P0 = wsum[0] + wsum[1] + wsum[2] + wsum[3];

    // Phase 2: local inclusive scan over the TP tile positions (wave 0).
    if (wave == 0 && lane < TP) {
        const int s = p0 + lane;
        const int t = trow[s];
        int inc = (t == sep && s < len) ? 1 : 0;
        #pragma unroll
        for (int off = 1; off < TP; off <<= 1) {
            int up = __shfl_up(inc, off);
            if (lane >= off) inc += up;
        }
        int sg = P0 + inc;
        if (sg >= nseg) sg = nseg - 1;                // JAX clamp-gather
        seg_lds[lane] = (s < len) ? sg : -1;
        tok_lds[lane] = (t < 0) ? 0 : ((t >= V) ? V - 1 : t);
    }
    __syncthreads();                                  // B2

    // Phase 3: gather + add + nontemporal store. One position per wave/iter.
    const size_t out_base = ((size_t)b * S + p0) * 64;
    #pragma unroll
    for (int k = 0; k < TP / 4; ++k) {
        const int pi = wave + k * 4;
        const int sg = seg_lds[pi];
        f32x4 r = (f32x4)0.f;
        if (sg >= 0) {
            const int t = tok_lds[pi];
            const f32x4 a = tok_emb[((size_t)t  << 6) + lane];
            const f32x4 e = seg_emb[((size_t)sg << 6) + lane];
            r = a + e;
        }
        __builtin_nontemporal_store(r, &out[out_base + (size_t)pi * 64 + lane]);
    }
}

// ---------------------------------------------------------------------------
// Generic fallback (R3 two-kernel path) for shapes the fused kernel
// doesn't cover.
// ---------------------------------------------------------------------------
__global__ __launch_bounds__(1024) void seg_scan_kernel(
        const int* __restrict__ tokens,
        const int* __restrict__ lengths,
        const int* __restrict__ sep_p,
        int* __restrict__ seg,
        int S) {
    const int b    = blockIdx.x;
    const int tid  = threadIdx.x;
    const int lane = tid & 63;
    const int wave = tid >> 6;
    const int sep  = sep_p[0];
    const int len  = lengths[b];
    const int* trow = tokens + (size_t)b * S;
    int* srow       = seg    + (size_t)b * S;

    __shared__ int wsum[16];
    __shared__ int carry_s;
    if (tid == 0) carry_s = 0;

    const int CHUNK = 4096;
    for (int base = 0; base < S; base += CHUNK) {
        const int s0 = base + tid * 4;
        int t0 = 0, t1 = 0, t2 = 0, t3 = 0;
        if (s0 + 3 < S) {
            const i32x4 t4 = *reinterpret_cast<const i32x4*>(trow + s0);
            t0 = t4.x; t1 = t4.y; t2 = t4.z; t3 = t4.w;
        } else {
            if (s0 + 0 < S) t0 = trow[s0 + 0];
            if (s0 + 1 < S) t1 = trow[s0 + 1];
            if (s0 + 2 < S) t2 = trow[s0 + 2];
            if (s0 + 3 < S) t3 = trow[s0 + 3];
        }
        int v0 = ((t0 == sep) && (s0 + 0 < len)) ? 1 : 0;
        int v1 = v0 + (((t1 == sep) && (s0 + 1 < len)) ? 1 : 0);
        int v2 = v1 + (((t2 == sep) && (s0 + 2 < len)) ? 1 : 0);
        int v3 = v2 + (((t3 == sep) && (s0 + 3 < len)) ? 1 : 0);
        const int cnt = v3;

        int ws = cnt;
        #pragma unroll
        for (int off = 1; off < 64; off <<= 1) {
            int up = __shfl_up(ws, off);
            if (lane >= off) ws += up;
        }
        if (lane == 63) wsum[wave] = ws;
        __syncthreads();

        int wave_excl = 0, total = 0;
        #pragma unroll
        for (int w = 0; w < 16; ++w) {
            int t = wsum[w];
            if (w < wave) wave_excl += t;
            total += t;
        }
        const int carry = carry_s;
        const int excl  = carry + wave_excl + (ws - cnt);

        if (s0 + 3 < S && s0 + 4 <= len) {
            i32x4 o; o.x = excl + v0; o.y = excl + v1; o.z = excl + v2; o.w = excl + v3;
            *reinterpret_cast<i32x4*>(srow + s0) = o;
        } else {
            if (s0 + 0 < S) srow[s0 + 0] = (s0 + 0 < len) ? excl + v0 : -1;
            if (s0 + 1 < S) srow[s0 + 1] = (s0 + 1 < len) ? excl + v1 : -1;
            if (s0 + 2 < S) srow[s0 + 2] = (s0 + 2 < len) ? excl + v2 : -1;
            if (s0 + 3 < S) srow[s0 + 3] = (s0 + 3 < len) ? excl + v3 : -1;
        }
        __syncthreads();
        if (tid == 0) carry_s = carry + total;
    }
}

__global__ __launch_bounds__(256) void gather_add_div_kernel(
        const f32x4* __restrict__ tok_emb,
        const f32x4* __restrict__ seg_emb,
        const int* __restrict__ tokens,
        const int* __restrict__ seg,
        f32x4* __restrict__ out,
        int D4, int nseg, int V, long long total) {
    const long long tid = (long long)blockIdx.x * blockDim.x + threadIdx.x;
    if (tid >= total) return;
    const int lane = (int)(tid % D4);
    const long long pos = tid / D4;

    const int sg_raw = seg[pos];
    f32x4 r = (f32x4)0.f;
    if (sg_raw >= 0) {
        int t = tokens[pos];
        t = (t < 0) ? 0 : ((t >= V) ? V - 1 : t);
        int sg = (sg_raw >= nseg) ? nseg - 1 : sg_raw;
        const f32x4 a = tok_emb[(size_t)t * D4 + lane];
        const f32x4 e = seg_emb[(size_t)sg * D4 + lane];
        r = a + e;
    }
    __builtin_nontemporal_store(r, &out[(size_t)pos * D4 + lane]);
}

extern "C" void kernel_launch(void* const* d_in, const int* in_sizes, int n_in,
                              void* d_out, int out_size, void* d_ws, size_t ws_size,
                              hipStream_t stream) {
    const float* tok_emb = (const float*)d_in[0];   // [V, D]
    const float* seg_emb = (const float*)d_in[1];   // [NSEG, D]
    const int*   tokens  = (const int*)d_in[2];     // [B, S]
    const int*   lengths = (const int*)d_in[3];     // [B]
    const int*   sep_p   = (const int*)d_in[4];     // scalar

    const int B    = in_sizes[3];
    const int BS   = in_sizes[2];
    const int S    = BS / B;
    const int D    = out_size / BS;
    const int nseg = in_sizes[1] / D;
    const int V    = in_sizes[0] / D;
    const int D4   = D / 4;

    constexpr int TP = 16;
    if (D4 == 64 && (S % TP) == 0) {
        const int grid = BS / TP;
        fused_embed_kernel<TP><<<grid, 256, 0, stream>>>(
            (const f32x4*)tok_emb, (const f32x4*)seg_emb,
            tokens, lengths, sep_p, (f32x4*)d_out, S, nseg, V);
    } else {
        int* seg_ws = (int*)d_ws;
        seg_scan_kernel<<<B, 1024, 0, stream>>>(tokens, lengths, sep_p, seg_ws, S);
        const long long total = (long long)BS * D4;
        const int block = 256;
        const int grid  = (int)((total + block - 1) / block);
        gather_add_div_kernel<<<grid, block, 0, stream>>>(
            (const f32x4*)tok_emb, (const f32x4*)seg_emb,
            tokens, seg_ws, (f32x4*)d_out, D4, nseg, V, total);
    }
}